// Round 1
// baseline (48747.870 us; speedup 1.0000x reference)
//
#include <hip/hip_runtime.h>
#include <hip/hip_bf16.h>
#include <stdint.h>

// Bidirectional GRU decoder: B=64, S=512, D=H=512, L=2.
// Phase plan:
//   convert_x, convert_wi  -> bf16 operands (feature-reversal folded into W_ih_b layer 0)
//   gemm_bt_bias x2        -> GI (layer 0, both dirs)  [32768 x 3072] bf16, +b_ih
//   scan (persistent)      -> layer 0 over 512 steps, writes X1f/X1b (bf16, overlaid in d_out)
//   gemm_bt_bias x2        -> GI (layer 1)
//   scan (persistent)      -> layer 1, writes out (B,S,2H) + out2 (B,2H) fp32
// Sequential half uses a device-scope software grid barrier (256 blocks = 1/CU, co-resident).

#define S_LEN 512
#define NCOL 3072
#define M_ROWS 32768
#define NBLK 256

typedef __attribute__((ext_vector_type(4))) float f32x4;
typedef __attribute__((ext_vector_type(8))) short s16x8;
typedef __attribute__((ext_vector_type(8))) unsigned short u16x8;

// ---------------- prep kernels ----------------

// Xbf[(t*64+b)*512 + d] = bf16(input[b][t][d])   (t-major rows so scan reads GI contiguously)
__global__ void convert_x_kernel(const float* __restrict__ in, __hip_bfloat16* __restrict__ xbf) {
  int idx = blockIdx.x * 256 + threadIdx.x;       // 16,777,216 total
  int d = idx & 511;
  int m = idx >> 9;
  int b = m & 63, t = m >> 6;
  xbf[idx] = __float2bfloat16(in[((size_t)b * S_LEN + t) * 512 + d]);
}

// WI blocks: 0=W_ih_f[0], 1=W_ih_b[0] feature-reversed, 2=W_ih_f[1], 3=W_ih_b[1]; each [1536][512] bf16
__global__ void convert_wi_kernel(const float* __restrict__ wf, const float* __restrict__ wb,
                                  __hip_bfloat16* __restrict__ wo) {
  int idx = blockIdx.x * 256 + threadIdx.x;       // 3,145,728 total
  int k = idx & 511;
  int row = idx >> 9;                              // 0..6143
  int blk = row / 1536;
  int j = row - blk * 1536;
  float v;
  if (blk == 0)      v = wf[(size_t)j * 512 + k];
  else if (blk == 1) v = wb[(size_t)j * 512 + (511 - k)];   // xb = x[:, ::-1] folded into weights
  else if (blk == 2) v = wf[(size_t)(1536 + j) * 512 + k];
  else               v = wb[(size_t)(1536 + j) * 512 + k];
  wo[idx] = __float2bfloat16(v);
}

// hbb[dir][pp=0][b][k] = bf16(encoder_h[b][dir*512+k])
__global__ void hinit_kernel(const float* __restrict__ enc, __hip_bfloat16* __restrict__ hbb) {
  int idx = blockIdx.x * 256 + threadIdx.x;       // 65,536 total
  int k = idx & 511;
  int bb = (idx >> 9) & 63;
  int dir = idx >> 15;
  hbb[(size_t)dir * 2 * 64 * 512 + (size_t)bb * 512 + k] =
      __float2bfloat16(enc[(size_t)bb * 1024 + dir * 512 + k]);
}

// ---------------- GI GEMM: C[m][col0+n] = sum_k A[m][k]*W[n][k] + bias[n] ----------------
// A: [32768][512] bf16, W: [1536][512] bf16 (B^T form), C: [32768][3072] bf16.
// 128x128 tile, BK=32, 4 waves, 16x16x32 bf16 MFMA, simple reg-staged LDS.
__global__ __launch_bounds__(256) void gemm_bt_bias(
    const __hip_bfloat16* __restrict__ A,
    const __hip_bfloat16* __restrict__ W,
    const float* __restrict__ bias,
    __hip_bfloat16* __restrict__ C,
    int col0) {
  __shared__ __hip_bfloat16 As[128 * 32];
  __shared__ __hip_bfloat16 Ws[128 * 32];
  const int tid = threadIdx.x;
  const int lane = tid & 63;
  const int w = tid >> 6;
  const int bn = blockIdx.x * 128;
  const int bm = blockIdx.y * 128;
  const int wm = (w >> 1) * 64, wn = (w & 1) * 64;
  const int r16 = lane & 15;
  const int koff = (lane >> 4) * 8;

  f32x4 acc[4][4];
#pragma unroll
  for (int i = 0; i < 4; ++i)
#pragma unroll
    for (int j = 0; j < 4; ++j) acc[i][j] = (f32x4){0.f, 0.f, 0.f, 0.f};

  for (int kt = 0; kt < 512; kt += 32) {
    __syncthreads();   // protect LDS from previous iteration's readers
#pragma unroll
    for (int i = 0; i < 2; ++i) {
      int seg = i * 256 + tid;                  // 0..511, 16B segments
      int row = seg >> 2, cs = seg & 3;
      *(s16x8*)&As[seg * 8] = *(const s16x8*)(A + ((size_t)(bm + row) << 9) + kt + cs * 8);
      *(s16x8*)&Ws[seg * 8] = *(const s16x8*)(W + ((size_t)(bn + row) << 9) + kt + cs * 8);
    }
    __syncthreads();
    s16x8 af[4], wfr[4];
#pragma unroll
    for (int i = 0; i < 4; ++i) {
      af[i]  = *(const s16x8*)&As[(wm + i * 16 + r16) * 32 + koff];
      wfr[i] = *(const s16x8*)&Ws[(wn + i * 16 + r16) * 32 + koff];
    }
#pragma unroll
    for (int i = 0; i < 4; ++i)
#pragma unroll
      for (int j = 0; j < 4; ++j)
        acc[i][j] = __builtin_amdgcn_mfma_f32_16x16x32_bf16(af[i], wfr[j], acc[i][j], 0, 0, 0);
  }

  const int rq = (lane >> 4) * 4;
#pragma unroll
  for (int j = 0; j < 4; ++j) {
    int n = bn + wn + j * 16 + r16;
    float bv = bias[n];
#pragma unroll
    for (int i = 0; i < 4; ++i) {
#pragma unroll
      for (int q = 0; q < 4; ++q) {
        int m = bm + wm + i * 16 + rq + q;
        C[(size_t)m * NCOL + col0 + n] = __float2bfloat16(acc[i][j][q] + bv);
      }
    }
  }
}

// ---------------- persistent scan ----------------
// 256 blocks x 512 threads. block: dir = bid>>7, owns hidden cols j4..j4+3 (12 gate cols).
// threads: b = tid&63 (lane), kseg = tid>>6 (wave). W_hh slice resident in LDS all 512 steps.
__global__ __launch_bounds__(512) void scan_kernel(
    const float* __restrict__ Whf, const float* __restrict__ Whb,   // [1536][512] this layer
    const float* __restrict__ bhf, const float* __restrict__ bhb,   // [1536]
    const __hip_bfloat16* __restrict__ GI,                           // [32768][3072]
    __hip_bfloat16* __restrict__ X1f, __hip_bfloat16* __restrict__ X1b,
    float* out, float* out2,
    __hip_bfloat16* hbb,                                             // [2][2][64][512] bf16
    int* bar, int last) {
  __shared__ float Wlds[12][512];     // 24 KB
  __shared__ float bh_lds[12];
  __shared__ float red[8][64][12];    // 24 KB

  const int tid = threadIdx.x;
  const int bid = blockIdx.x;
  const int dir = bid >> 7;
  const int j4 = (bid & 127) * 4;
  const float* Wsrc = dir ? Whb : Whf;
  const float* bhsrc = dir ? bhb : bhf;

  for (int idx = tid; idx < 12 * 512; idx += 512) {
    int c = idx >> 9, k = idx & 511;
    int jc = c / 3, g = c - jc * 3;
    Wlds[c][k] = Wsrc[((size_t)(g * 512 + j4 + jc) << 9) + k];
  }
  if (tid < 12) {
    int jc = tid / 3, g = tid - jc * 3;
    bh_lds[tid] = bhsrc[g * 512 + j4 + jc];
  }
  __syncthreads();

  const int b = tid & 63;
  const int kseg = tid >> 6;
  __hip_bfloat16* hd = hbb + (size_t)dir * 2 * 64 * 512;

  int gen = 0;
  if (tid == 0) gen = __hip_atomic_load(&bar[1], __ATOMIC_RELAXED, __HIP_MEMORY_SCOPE_AGENT);

  for (int t = 0; t < S_LEN; ++t) {
    const int pp = t & 1;
    // ---- load h[b][kseg*64..+63] into registers (bf16 -> f32 by shift) ----
    const __hip_bfloat16* hrow = hd + (size_t)pp * 32768 + (size_t)b * 512 + kseg * 64;
    float hreg[64];
#pragma unroll
    for (int i = 0; i < 8; ++i) {
      u16x8 hv = *(const u16x8*)(hrow + i * 8);
#pragma unroll
      for (int e = 0; e < 8; ++e) hreg[i * 8 + e] = __uint_as_float((unsigned)hv[e] << 16);
    }
    // ---- 12 partial dot products over this k-segment (W reads are wave-uniform broadcasts) ----
    float acc[12];
#pragma unroll
    for (int c = 0; c < 12; ++c) acc[c] = 0.f;
#pragma unroll
    for (int c = 0; c < 12; ++c) {
      const float* wrow = &Wlds[c][kseg * 64];
#pragma unroll
      for (int k4 = 0; k4 < 16; ++k4) {
        f32x4 wv = *(const f32x4*)(wrow + k4 * 4);
        acc[c] += hreg[k4 * 4 + 0] * wv.x + hreg[k4 * 4 + 1] * wv.y +
                  hreg[k4 * 4 + 2] * wv.z + hreg[k4 * 4 + 3] * wv.w;
      }
    }
    *(f32x4*)&red[kseg][b][0] = (f32x4){acc[0], acc[1], acc[2], acc[3]};
    *(f32x4*)&red[kseg][b][4] = (f32x4){acc[4], acc[5], acc[6], acc[7]};
    *(f32x4*)&red[kseg][b][8] = (f32x4){acc[8], acc[9], acc[10], acc[11]};
    __syncthreads();

    // ---- gates: threads 0..255 = (b, jc) ----
    if (tid < 256) {
      const int jc = tid >> 6;
      float gr = 0.f, gz = 0.f, gn2 = 0.f;
#pragma unroll
      for (int ks = 0; ks < 8; ++ks) {
        gr  += red[ks][b][jc * 3 + 0];
        gz  += red[ks][b][jc * 3 + 1];
        gn2 += red[ks][b][jc * 3 + 2];
      }
      const int j = j4 + jc;
      const size_t m = (size_t)t * 64 + b;
      const __hip_bfloat16* gi = GI + m * NCOL + dir * 1536;
      float ir = __bfloat162float(gi[j]);
      float iz = __bfloat162float(gi[512 + j]);
      float in_ = __bfloat162float(gi[1024 + j]);
      float r = 1.f / (1.f + __expf(-(ir + gr + bh_lds[jc * 3 + 0])));
      float z = 1.f / (1.f + __expf(-(iz + gz + bh_lds[jc * 3 + 1])));
      float hn = gn2 + bh_lds[jc * 3 + 2];
      float x2 = ir * 0.f + 2.f * (in_ + r * hn);       // tanh via exp
      float n = 1.f - 2.f / (1.f + __expf(x2));
      float hold = __bfloat162float(hd[(size_t)pp * 32768 + (size_t)b * 512 + j]);
      float hnew = (1.f - z) * n + z * hold;
      hd[(size_t)(pp ^ 1) * 32768 + (size_t)b * 512 + j] = __float2bfloat16(hnew);
      if (!last) {
        (dir ? X1b : X1f)[m * 512 + j] = __float2bfloat16(hnew);
      } else {
        out[((size_t)b * 512 + t) * 1024 + dir * 512 + j] = hnew;
        if (t == S_LEN - 1) out2[(size_t)b * 1024 + dir * 512 + j] = hnew;
      }
    }

    // ---- device-scope grid barrier ----
    __syncthreads();
    if (tid == 0) {
      __threadfence();
      int old = __hip_atomic_fetch_add(&bar[0], 1, __ATOMIC_ACQ_REL, __HIP_MEMORY_SCOPE_AGENT);
      if (old == NBLK - 1) {
        __hip_atomic_store(&bar[0], 0, __ATOMIC_RELAXED, __HIP_MEMORY_SCOPE_AGENT);
        __hip_atomic_fetch_add(&bar[1], 1, __ATOMIC_RELEASE, __HIP_MEMORY_SCOPE_AGENT);
      } else {
        while (__hip_atomic_load(&bar[1], __ATOMIC_ACQUIRE, __HIP_MEMORY_SCOPE_AGENT) < gen + 1)
          __builtin_amdgcn_s_sleep(1);
      }
      gen++;
    }
    __syncthreads();
  }
}

// ---------------- launch ----------------
extern "C" void kernel_launch(void* const* d_in, const int* in_sizes, int n_in,
                              void* d_out, int out_size, void* d_ws, size_t ws_size,
                              hipStream_t stream) {
  (void)in_sizes; (void)n_in; (void)out_size; (void)ws_size;
  const float* input = (const float*)d_in[0];
  const float* enc_h = (const float*)d_in[2];
  const float* Wihf  = (const float*)d_in[3];
  const float* Whhf  = (const float*)d_in[4];
  const float* bihf  = (const float*)d_in[5];
  const float* bhhf  = (const float*)d_in[6];
  const float* Wihb  = (const float*)d_in[7];
  const float* Whhb  = (const float*)d_in[8];
  const float* bihb  = (const float*)d_in[9];
  const float* bhhb  = (const float*)d_in[10];

  float* out  = (float*)d_out;
  float* out2 = out + (size_t)M_ROWS * 1024;

  char* ws = (char*)d_ws;
  int* bar = (int*)ws;
  __hip_bfloat16* Xbf = (__hip_bfloat16*)(ws + 256);
  __hip_bfloat16* WI  = (__hip_bfloat16*)(ws + 256 + 33554432ull);
  __hip_bfloat16* GI  = (__hip_bfloat16*)(ws + 256 + 33554432ull + 6291456ull);
  __hip_bfloat16* hbb = (__hip_bfloat16*)(ws + 256 + 33554432ull + 6291456ull + 201326592ull);
  // X1 (layer-0 outputs, bf16) overlaid into d_out: fully rewritten by layer-1 scan afterwards.
  __hip_bfloat16* X1f = (__hip_bfloat16*)d_out;
  __hip_bfloat16* X1b = X1f + (size_t)M_ROWS * 512;

  hipMemsetAsync(ws, 0, 256, stream);
  convert_x_kernel<<<65536, 256, 0, stream>>>(input, Xbf);
  convert_wi_kernel<<<12288, 256, 0, stream>>>(Wihf, Wihb, WI);
  hinit_kernel<<<256, 256, 0, stream>>>(enc_h, hbb);

  dim3 gg(12, 256);
  gemm_bt_bias<<<gg, 256, 0, stream>>>(Xbf, WI,               bihf,        GI, 0);
  gemm_bt_bias<<<gg, 256, 0, stream>>>(Xbf, WI + 786432,      bihb,        GI, 1536);
  scan_kernel<<<NBLK, 512, 0, stream>>>(Whhf, Whhb, bhhf, bhhb, GI, X1f, X1b,
                                        out, out2, hbb, bar, 0);
  gemm_bt_bias<<<gg, 256, 0, stream>>>(X1f, WI + 2 * 786432,  bihf + 1536, GI, 0);
  gemm_bt_bias<<<gg, 256, 0, stream>>>(X1b, WI + 3 * 786432,  bihb + 1536, GI, 1536);
  hinit_kernel<<<256, 256, 0, stream>>>(enc_h, hbb);
  scan_kernel<<<NBLK, 512, 0, stream>>>(Whhf + 786432, Whhb + 786432, bhhf + 1536, bhhb + 1536,
                                        GI, X1f, X1b, out, out2, hbb, bar, 1);
}

// Round 3
// 31740.207 us; speedup vs baseline: 1.5358x; 1.5358x over previous
//
#include <hip/hip_runtime.h>
#include <hip/hip_bf16.h>
#include <stdint.h>

// Bidirectional GRU decoder: B=64, S=512, D=H=512, L=2.
// Phase plan:
//   convert_x, convert_wi  -> bf16 operands (feature-reversal folded into W_ih_b layer 0)
//   gemm_bt_bias x2        -> GI (layer 0, both dirs)  [32768 x 3072] bf16, +b_ih
//   scan (persistent)      -> layer 0 over 512 steps, writes X1f/X1b (bf16, overlaid in d_out)
//   gemm_bt_bias x2        -> GI (layer 1)
//   scan (persistent)      -> layer 1, writes out (B,S,2H) + out2 (B,2H) fp32
// Grid sync: RMW-free flag-array barrier (R1 post-mortem: single-line atomicAdd
// from 256 blocks serialized cross-XCD at ~48 us/step = 100% of runtime).

#define S_LEN 512
#define NCOL 3072
#define M_ROWS 32768
#define NBLK 256

typedef __attribute__((ext_vector_type(4))) float f32x4;
typedef __attribute__((ext_vector_type(8))) short s16x8;
typedef __attribute__((ext_vector_type(8))) unsigned short u16x8;

// ---------------- prep kernels ----------------

// Xbf[(t*64+b)*512 + d] = bf16(input[b][t][d])   (t-major rows so scan reads GI contiguously)
__global__ void convert_x_kernel(const float* __restrict__ in, __hip_bfloat16* __restrict__ xbf) {
  int idx = blockIdx.x * 256 + threadIdx.x;       // 16,777,216 total
  int d = idx & 511;
  int m = idx >> 9;
  int b = m & 63, t = m >> 6;
  xbf[idx] = __float2bfloat16(in[((size_t)b * S_LEN + t) * 512 + d]);
}

// WI blocks: 0=W_ih_f[0], 1=W_ih_b[0] feature-reversed, 2=W_ih_f[1], 3=W_ih_b[1]; each [1536][512] bf16
__global__ void convert_wi_kernel(const float* __restrict__ wf, const float* __restrict__ wb,
                                  __hip_bfloat16* __restrict__ wo) {
  int idx = blockIdx.x * 256 + threadIdx.x;       // 3,145,728 total
  int k = idx & 511;
  int row = idx >> 9;                              // 0..6143
  int blk = row / 1536;
  int j = row - blk * 1536;
  float v;
  if (blk == 0)      v = wf[(size_t)j * 512 + k];
  else if (blk == 1) v = wb[(size_t)j * 512 + (511 - k)];   // xb = x[:, ::-1] folded into weights
  else if (blk == 2) v = wf[(size_t)(1536 + j) * 512 + k];
  else               v = wb[(size_t)(1536 + j) * 512 + k];
  wo[idx] = __float2bfloat16(v);
}

// hbb[dir][pp=0][b][k] = bf16(encoder_h[b][dir*512+k])
__global__ void hinit_kernel(const float* __restrict__ enc, __hip_bfloat16* __restrict__ hbb) {
  int idx = blockIdx.x * 256 + threadIdx.x;       // 65,536 total
  int k = idx & 511;
  int bb = (idx >> 9) & 63;
  int dir = idx >> 15;
  hbb[(size_t)dir * 2 * 64 * 512 + (size_t)bb * 512 + k] =
      __float2bfloat16(enc[(size_t)bb * 1024 + dir * 512 + k]);
}

// ---------------- GI GEMM: C[m][col0+n] = sum_k A[m][k]*W[n][k] + bias[n] ----------------
// A: [32768][512] bf16, W: [1536][512] bf16 (B^T form), C: [32768][3072] bf16.
// 128x128 tile, BK=32, 4 waves, 16x16x32 bf16 MFMA, simple reg-staged LDS.
__global__ __launch_bounds__(256) void gemm_bt_bias(
    const __hip_bfloat16* __restrict__ A,
    const __hip_bfloat16* __restrict__ W,
    const float* __restrict__ bias,
    __hip_bfloat16* __restrict__ C,
    int col0) {
  __shared__ __hip_bfloat16 As[128 * 32];
  __shared__ __hip_bfloat16 Ws[128 * 32];
  const int tid = threadIdx.x;
  const int lane = tid & 63;
  const int w = tid >> 6;
  const int bn = blockIdx.x * 128;
  const int bm = blockIdx.y * 128;
  const int wm = (w >> 1) * 64, wn = (w & 1) * 64;
  const int r16 = lane & 15;
  const int koff = (lane >> 4) * 8;

  f32x4 acc[4][4];
#pragma unroll
  for (int i = 0; i < 4; ++i)
#pragma unroll
    for (int j = 0; j < 4; ++j) acc[i][j] = (f32x4){0.f, 0.f, 0.f, 0.f};

  for (int kt = 0; kt < 512; kt += 32) {
    __syncthreads();   // protect LDS from previous iteration's readers
#pragma unroll
    for (int i = 0; i < 2; ++i) {
      int seg = i * 256 + tid;                  // 0..511, 16B segments
      int row = seg >> 2, cs = seg & 3;
      *(s16x8*)&As[seg * 8] = *(const s16x8*)(A + ((size_t)(bm + row) << 9) + kt + cs * 8);
      *(s16x8*)&Ws[seg * 8] = *(const s16x8*)(W + ((size_t)(bn + row) << 9) + kt + cs * 8);
    }
    __syncthreads();
    s16x8 af[4], wfr[4];
#pragma unroll
    for (int i = 0; i < 4; ++i) {
      af[i]  = *(const s16x8*)&As[(wm + i * 16 + r16) * 32 + koff];
      wfr[i] = *(const s16x8*)&Ws[(wn + i * 16 + r16) * 32 + koff];
    }
#pragma unroll
    for (int i = 0; i < 4; ++i)
#pragma unroll
      for (int j = 0; j < 4; ++j)
        acc[i][j] = __builtin_amdgcn_mfma_f32_16x16x32_bf16(af[i], wfr[j], acc[i][j], 0, 0, 0);
  }

  const int rq = (lane >> 4) * 4;
#pragma unroll
  for (int j = 0; j < 4; ++j) {
    int n = bn + wn + j * 16 + r16;
    float bv = bias[n];
#pragma unroll
    for (int i = 0; i < 4; ++i) {
#pragma unroll
      for (int q = 0; q < 4; ++q) {
        int m = bm + wm + i * 16 + rq + q;
        C[(size_t)m * NCOL + col0 + n] = __float2bfloat16(acc[i][j][q] + bv);
      }
    }
  }
}

// ---------------- persistent scan ----------------
// 256 blocks x 512 threads. block: dir = bid>>7, owns hidden cols j4..j4+3 (12 gate cols).
// threads: b = tid&63 (lane), kseg = tid>>6 (wave). W_hh slice resident in LDS all 512 steps.
// Barrier: flag-array. Arrival = 1 release store per block (16 cache lines total, no RMW
// contention); wait = wave 0 of EVERY block polls all 256 flags (1 KB pipelined L3 read).
__global__ __launch_bounds__(512) void scan_kernel(
    const float* __restrict__ Whf, const float* __restrict__ Whb,   // [1536][512] this layer
    const float* __restrict__ bhf, const float* __restrict__ bhb,   // [1536]
    const __hip_bfloat16* __restrict__ GI,                           // [32768][3072]
    __hip_bfloat16* __restrict__ X1f, __hip_bfloat16* __restrict__ X1b,
    float* out, float* out2,
    __hip_bfloat16* hbb,                                             // [2][2][64][512] bf16
    int* arrive, int gen_base, int last) {
  __shared__ float Wlds[12][512];     // 24 KB
  __shared__ float bh_lds[12];
  __shared__ float red[8][64][12];    // 24 KB

  const int tid = threadIdx.x;
  const int bid = blockIdx.x;
  const int dir = bid >> 7;
  const int j4 = (bid & 127) * 4;
  const float* Wsrc = dir ? Whb : Whf;
  const float* bhsrc = dir ? bhb : bhf;

  for (int idx = tid; idx < 12 * 512; idx += 512) {
    int c = idx >> 9, k = idx & 511;
    int jc = c / 3, g = c - jc * 3;
    Wlds[c][k] = Wsrc[((size_t)(g * 512 + j4 + jc) << 9) + k];
  }
  if (tid < 12) {
    int jc = tid / 3, g = tid - jc * 3;
    bh_lds[tid] = bhsrc[g * 512 + j4 + jc];
  }
  __syncthreads();

  const int b = tid & 63;
  const int kseg = tid >> 6;
  __hip_bfloat16* hd = hbb + (size_t)dir * 2 * 64 * 512;

  for (int t = 0; t < S_LEN; ++t) {
    const int pp = t & 1;
    // ---- load h[b][kseg*64..+63] into registers (bf16 -> f32 by shift) ----
    const __hip_bfloat16* hrow = hd + (size_t)pp * 32768 + (size_t)b * 512 + kseg * 64;
    float hreg[64];
#pragma unroll
    for (int i = 0; i < 8; ++i) {
      u16x8 hv = *(const u16x8*)(hrow + i * 8);
#pragma unroll
      for (int e = 0; e < 8; ++e) hreg[i * 8 + e] = __uint_as_float((unsigned)hv[e] << 16);
    }
    // ---- 12 partial dot products over this k-segment (W reads are wave-uniform broadcasts) ----
    float acc[12];
#pragma unroll
    for (int c = 0; c < 12; ++c) acc[c] = 0.f;
#pragma unroll
    for (int c = 0; c < 12; ++c) {
      const float* wrow = &Wlds[c][kseg * 64];
#pragma unroll
      for (int k4 = 0; k4 < 16; ++k4) {
        f32x4 wv = *(const f32x4*)(wrow + k4 * 4);
        acc[c] += hreg[k4 * 4 + 0] * wv.x + hreg[k4 * 4 + 1] * wv.y +
                  hreg[k4 * 4 + 2] * wv.z + hreg[k4 * 4 + 3] * wv.w;
      }
    }
    *(f32x4*)&red[kseg][b][0] = (f32x4){acc[0], acc[1], acc[2], acc[3]};
    *(f32x4*)&red[kseg][b][4] = (f32x4){acc[4], acc[5], acc[6], acc[7]};
    *(f32x4*)&red[kseg][b][8] = (f32x4){acc[8], acc[9], acc[10], acc[11]};
    __syncthreads();

    // ---- gates: threads 0..255 = (b, jc) ----
    if (tid < 256) {
      const int jc = tid >> 6;
      float gr = 0.f, gz = 0.f, gn2 = 0.f;
#pragma unroll
      for (int ks = 0; ks < 8; ++ks) {
        gr  += red[ks][b][jc * 3 + 0];
        gz  += red[ks][b][jc * 3 + 1];
        gn2 += red[ks][b][jc * 3 + 2];
      }
      const int j = j4 + jc;
      const size_t m = (size_t)t * 64 + b;
      const __hip_bfloat16* gi = GI + m * NCOL + dir * 1536;
      float ir = __bfloat162float(gi[j]);
      float iz = __bfloat162float(gi[512 + j]);
      float in_ = __bfloat162float(gi[1024 + j]);
      float r = 1.f / (1.f + __expf(-(ir + gr + bh_lds[jc * 3 + 0])));
      float z = 1.f / (1.f + __expf(-(iz + gz + bh_lds[jc * 3 + 1])));
      float hn = gn2 + bh_lds[jc * 3 + 2];
      float x2 = 2.f * (in_ + r * hn);
      float n = 1.f - 2.f / (1.f + __expf(x2));       // tanh via exp
      float hold = __bfloat162float(hd[(size_t)pp * 32768 + (size_t)b * 512 + j]);
      float hnew = (1.f - z) * n + z * hold;
      hd[(size_t)(pp ^ 1) * 32768 + (size_t)b * 512 + j] = __float2bfloat16(hnew);
      if (!last) {
        (dir ? X1b : X1f)[m * 512 + j] = __float2bfloat16(hnew);
      } else {
        out[((size_t)b * 512 + t) * 1024 + dir * 512 + j] = hnew;
        if (t == S_LEN - 1) out2[(size_t)b * 1024 + dir * 512 + j] = hnew;
      }
    }

    // ---- flag-array grid barrier (no RMW contention) ----
    __syncthreads();
    const int target = gen_base + t + 1;
    if (tid == 0) {
      __threadfence();   // agent-scope: write back this XCD's dirty L2 (covers all block's h stores)
      __hip_atomic_store(&arrive[bid], target, __ATOMIC_RELEASE, __HIP_MEMORY_SCOPE_AGENT);
    }
    if (tid < 64) {
      for (;;) {
        int v0 = __hip_atomic_load(&arrive[tid],       __ATOMIC_RELAXED, __HIP_MEMORY_SCOPE_AGENT);
        int v1 = __hip_atomic_load(&arrive[tid + 64],  __ATOMIC_RELAXED, __HIP_MEMORY_SCOPE_AGENT);
        int v2 = __hip_atomic_load(&arrive[tid + 128], __ATOMIC_RELAXED, __HIP_MEMORY_SCOPE_AGENT);
        int v3 = __hip_atomic_load(&arrive[tid + 192], __ATOMIC_RELAXED, __HIP_MEMORY_SCOPE_AGENT);
        bool ok = (v0 >= target) & (v1 >= target) & (v2 >= target) & (v3 >= target);
        if (__all(ok)) break;
        __builtin_amdgcn_s_sleep(1);
      }
      __threadfence();   // acquire side: invalidate L1/L2 so next step's h reads are fresh
    }
    __syncthreads();
  }
}

// ---------------- launch ----------------
extern "C" void kernel_launch(void* const* d_in, const int* in_sizes, int n_in,
                              void* d_out, int out_size, void* d_ws, size_t ws_size,
                              hipStream_t stream) {
  (void)in_sizes; (void)n_in; (void)out_size; (void)ws_size;
  const float* input = (const float*)d_in[0];
  const float* enc_h = (const float*)d_in[2];
  const float* Wihf  = (const float*)d_in[3];
  const float* Whhf  = (const float*)d_in[4];
  const float* bihf  = (const float*)d_in[5];
  const float* bhhf  = (const float*)d_in[6];
  const float* Wihb  = (const float*)d_in[7];
  const float* Whhb  = (const float*)d_in[8];
  const float* bihb  = (const float*)d_in[9];
  const float* bhhb  = (const float*)d_in[10];

  float* out  = (float*)d_out;
  float* out2 = out + (size_t)M_ROWS * 1024;

  char* ws = (char*)d_ws;
  int* arrive = (int*)ws;                               // 256 ints
  __hip_bfloat16* Xbf = (__hip_bfloat16*)(ws + 4096);
  __hip_bfloat16* WI  = (__hip_bfloat16*)(ws + 4096 + 33554432ull);
  __hip_bfloat16* GI  = (__hip_bfloat16*)(ws + 4096 + 33554432ull + 6291456ull);
  __hip_bfloat16* hbb = (__hip_bfloat16*)(ws + 4096 + 33554432ull + 6291456ull + 201326592ull);
  // X1 (layer-0 outputs, bf16) overlaid into d_out: fully rewritten by layer-1 scan afterwards.
  __hip_bfloat16* X1f = (__hip_bfloat16*)d_out;
  __hip_bfloat16* X1b = X1f + (size_t)M_ROWS * 512;

  hipMemsetAsync(ws, 0, 4096, stream);
  convert_x_kernel<<<65536, 256, 0, stream>>>(input, Xbf);
  convert_wi_kernel<<<12288, 256, 0, stream>>>(Wihf, Wihb, WI);
  hinit_kernel<<<256, 256, 0, stream>>>(enc_h, hbb);

  dim3 gg(12, 256);
  gemm_bt_bias<<<gg, 256, 0, stream>>>(Xbf, WI,               bihf,        GI, 0);
  gemm_bt_bias<<<gg, 256, 0, stream>>>(Xbf, WI + 786432,      bihb,        GI, 1536);
  scan_kernel<<<NBLK, 512, 0, stream>>>(Whhf, Whhb, bhhf, bhhb, GI, X1f, X1b,
                                        out, out2, hbb, arrive, 0, 0);
  gemm_bt_bias<<<gg, 256, 0, stream>>>(X1f, WI + 2 * 786432,  bihf + 1536, GI, 0);
  gemm_bt_bias<<<gg, 256, 0, stream>>>(X1b, WI + 3 * 786432,  bihb + 1536, GI, 1536);
  hinit_kernel<<<256, 256, 0, stream>>>(enc_h, hbb);
  scan_kernel<<<NBLK, 512, 0, stream>>>(Whhf + 786432, Whhb + 786432, bhhf + 1536, bhhb + 1536,
                                        GI, X1f, X1b, out, out2, hbb, arrive, 512, 1);
}